// Round 2
// baseline (580.487 us; speedup 1.0000x reference)
//
#include <hip/hip_runtime.h>
#include <hip/hip_bf16.h>
#include <math.h>

#define NUM_ITEMS 50000
#define NUM_USERS 16384
#define H0 512
#define LAT 256
#define FP8_SCALE 64.0f   // weights ~±0.011 are subnormal in e4m3; x64 -> ~0.7 (3% rel err)
#define FP8_INV (1.0f / 64.0f)

typedef __attribute__((ext_vector_type(8))) short short8;
typedef __attribute__((ext_vector_type(4))) float floatx4;
typedef __attribute__((ext_vector_type(2))) float vf2;

__device__ __forceinline__ unsigned short f2bf(float f) {
    union { float f; unsigned i; } u; u.f = f;
    unsigned r = u.i + 0x7fff + ((u.i >> 16) & 1);   // RNE
    return (unsigned short)(r >> 16);
}
__device__ __forceinline__ float bfhi(unsigned v) {
    union { unsigned i; float f; } u; u.i = v & 0xffff0000u; return u.f;
}
__device__ __forceinline__ float bflo(unsigned v) {
    union { unsigned i; float f; } u; u.i = v << 16; return u.f;
}
__device__ __forceinline__ uint4 pack8(const float* v) {
    uint4 p;
    p.x = (unsigned)f2bf(v[0]) | ((unsigned)f2bf(v[1]) << 16);
    p.y = (unsigned)f2bf(v[2]) | ((unsigned)f2bf(v[3]) << 16);
    p.z = (unsigned)f2bf(v[4]) | ((unsigned)f2bf(v[5]) << 16);
    p.w = (unsigned)f2bf(v[6]) | ((unsigned)f2bf(v[7]) << 16);
    return p;
}
// pack 4 floats -> 4 fp8 e4m3 (OCP on gfx950)
__device__ __forceinline__ unsigned pkfp8_4(float a, float b, float c, float d) {
    int v = __builtin_amdgcn_cvt_pk_fp8_f32(a, b, 0, false);
    v = __builtin_amdgcn_cvt_pk_fp8_f32(c, d, v, true);
    return (unsigned)v;
}
__device__ __forceinline__ void fp8x4_to_f32(unsigned v, float* o) {
    vf2 lo = __builtin_amdgcn_cvt_pk_f32_fp8((int)v, false);
    vf2 hi = __builtin_amdgcn_cvt_pk_f32_fp8((int)v, true);
    o[0] = lo.x; o[1] = lo.y; o[2] = hi.x; o[3] = hi.y;
}

// ================= count: users (interactions) + users (targets) =================
__global__ __launch_bounds__(256) void count_kernel(const int* __restrict__ user, int* __restrict__ cntU,
                                                    const int* __restrict__ t_user, int* __restrict__ cntTU,
                                                    int n, int nt) {
    int i = (blockIdx.x * blockDim.x + threadIdx.x) * 4;
    if (i + 3 < n) {
        int4 u = *(const int4*)(user + i);
        atomicAdd(&cntU[u.x], 1); atomicAdd(&cntU[u.y], 1);
        atomicAdd(&cntU[u.z], 1); atomicAdd(&cntU[u.w], 1);
    } else {
        for (int k = i; k < n; ++k) atomicAdd(&cntU[user[k]], 1);
    }
    if (i + 3 < nt) {
        int4 t = *(const int4*)(t_user + i);
        atomicAdd(&cntTU[t.x], 1); atomicAdd(&cntTU[t.y], 1);
        atomicAdd(&cntTU[t.z], 1); atomicAdd(&cntTU[t.w], 1);
    } else {
        for (int k = i; k < nt; ++k) atomicAdd(&cntTU[t_user[k]], 1);
    }
}

// ================= dual exclusive scan =================
__device__ void scan_block(const int* __restrict__ cnt, int* __restrict__ offs,
                           int* __restrict__ cursor, int per) {
    __shared__ int ssum[1024];
    int t = threadIdx.x;
    int base = t * per;
    int s = 0;
    for (int j = 0; j < per; j += 4) {
        int4 v = *(const int4*)(cnt + base + j);
        s += v.x + v.y + v.z + v.w;
    }
    ssum[t] = s;
    __syncthreads();
    for (int off = 1; off < 1024; off <<= 1) {
        int v = (t >= off) ? ssum[t - off] : 0;
        __syncthreads();
        ssum[t] += v;
        __syncthreads();
    }
    int run = (t == 0) ? 0 : ssum[t - 1];
    for (int j = 0; j < per; j += 4) {
        int4 v = *(const int4*)(cnt + base + j);
        int4 o;
        o.x = run; run += v.x;
        o.y = run; run += v.y;
        o.z = run; run += v.z;
        o.w = run; run += v.w;
        *(int4*)(offs + base + j) = o;
        *(int4*)(cursor + base + j) = o;
    }
}

__global__ void scan_kernel(const int* __restrict__ cntU, int* __restrict__ offsU, int* __restrict__ curU,
                            const int* __restrict__ cntTU, int* __restrict__ offsTU, int* __restrict__ curTU) {
    if (blockIdx.x == 0) scan_block(cntU, offsU, curU, NUM_USERS / 1024);
    else scan_block(cntTU, offsTU, curTU, NUM_USERS / 1024);
}

// ================= mega kernel: scatter | transpose W_enc -> fp8 | W_dec -> fp8 | W1/W2 -> bf16 =================
// block ranges: [0,SB) scatter ; [SB,SB+TB) transpose ; [SB+TB,+DB) W_dec ; [+WB) W1/W2.
// LDS is 16KB -> 8 blocks/CU (32 waves, full cap) for every block type.
__global__ __launch_bounds__(256) void mega_kernel(
        const int* __restrict__ user, const int* __restrict__ item,
        const float* __restrict__ rating, int* __restrict__ curU, int2* __restrict__ s_pack,
        const int* __restrict__ t_user, const int* __restrict__ t_item,
        const float* __restrict__ t_rating, int* __restrict__ curTU, int4* __restrict__ st_pack,
        const float* __restrict__ W_enc, unsigned char* __restrict__ wtb8,
        const float* __restrict__ W_dec, unsigned char* __restrict__ wdb8,
        const float* __restrict__ W1, unsigned short* __restrict__ w1b,
        const float* __restrict__ W2, unsigned short* __restrict__ w2b,
        int n, int nt, int SB, int TB, int DB) {
    // [h][item] natural layout: float4 LDS stores on the load side (~2-way max),
    // transpose happens on the read side with stride-64 scalar reads (bank = item%32, conflict-free).
    __shared__ float tileh[64 * 64];    // 16 KB
    int bid = blockIdx.x;
    int tid = threadIdx.x;
    if (bid < SB) {
        // ---- scatter: interactions by user (int2), targets by user (int4) ----
        int i = bid * 256 + tid;
        if (i < n) {
            int u = user[i];
            int pos = atomicAdd(&curU[u], 1);
            s_pack[pos] = make_int2(item[i], __float_as_int(rating[i]));
        }
        if (i < nt) {
            int tu = t_user[i];
            int pos = atomicAdd(&curTU[tu], 1);
            st_pack[pos] = make_int4(t_item[i], __float_as_int(t_rating[i]), i, 0);
        }
    } else if (bid < SB + TB) {
        // ---- transpose W_enc [H0][NUM_ITEMS] f32 -> wtb8 [NUM_ITEMS][H0] fp8 (x64), 64it x 64h tiles ----
        const int TBX = (NUM_ITEMS + 63) / 64;   // 782
        int b = bid - SB;
        int x0 = (b % TBX) * 64;        // item base
        int y0 = (b / TBX) * 64;        // h base
        int g = tid >> 4;               // 0..15 h-sub
        int m = tid & 15;               // item quad
        int it4 = x0 + m * 4;
#pragma unroll
        for (int p = 0; p < 4; ++p) {
            int hloc = p * 16 + g;
            if (it4 < NUM_ITEMS) {
                float4 v = *(const float4*)(W_enc + (size_t)(y0 + hloc) * NUM_ITEMS + it4);
                *(float4*)(tileh + hloc * 64 + m * 4) = v;
            }
        }
        __syncthreads();
        int i = tid >> 2;               // item 0..63
        int l = tid & 3;                // 16-element h chunk
        int it = x0 + i;
        if (it < NUM_ITEMS) {
            const float* src = tileh + (l * 16) * 64 + i;   // stride-64 column reads
            uint4 o;
            o.x = pkfp8_4(src[0] * FP8_SCALE, src[64] * FP8_SCALE, src[128] * FP8_SCALE, src[192] * FP8_SCALE);
            o.y = pkfp8_4(src[256] * FP8_SCALE, src[320] * FP8_SCALE, src[384] * FP8_SCALE, src[448] * FP8_SCALE);
            o.z = pkfp8_4(src[512] * FP8_SCALE, src[576] * FP8_SCALE, src[640] * FP8_SCALE, src[704] * FP8_SCALE);
            o.w = pkfp8_4(src[768] * FP8_SCALE, src[832] * FP8_SCALE, src[896] * FP8_SCALE, src[960] * FP8_SCALE);
            *(uint4*)(wtb8 + (size_t)it * H0 + y0 + l * 16) = o;
        }
    } else if (bid < SB + TB + DB) {
        // ---- W_dec f32 -> fp8 (x64), 16 elems/thread, pure streaming ----
        size_t idx = (size_t)(bid - SB - TB) * 4096 + tid * 16;
        float4 v0 = *(const float4*)(W_dec + idx);
        float4 v1 = *(const float4*)(W_dec + idx + 4);
        float4 v2 = *(const float4*)(W_dec + idx + 8);
        float4 v3 = *(const float4*)(W_dec + idx + 12);
        uint4 o;
        o.x = pkfp8_4(v0.x * FP8_SCALE, v0.y * FP8_SCALE, v0.z * FP8_SCALE, v0.w * FP8_SCALE);
        o.y = pkfp8_4(v1.x * FP8_SCALE, v1.y * FP8_SCALE, v1.z * FP8_SCALE, v1.w * FP8_SCALE);
        o.z = pkfp8_4(v2.x * FP8_SCALE, v2.y * FP8_SCALE, v2.z * FP8_SCALE, v2.w * FP8_SCALE);
        o.w = pkfp8_4(v3.x * FP8_SCALE, v3.y * FP8_SCALE, v3.z * FP8_SCALE, v3.w * FP8_SCALE);
        *(uint4*)(wdb8 + idx) = o;
    } else {
        // ---- W1 / W2 cast to bf16, 64 blocks each ----
        int b2i = bid - SB - TB - DB;
        const float* src = (b2i < 64) ? W1 : W2;
        unsigned short* dst = (b2i < 64) ? w1b : w2b;
        int idx = (b2i & 63) * 2048 + tid * 8;
        float v[8];
        *(float4*)&v[0] = *(const float4*)(src + idx);
        *(float4*)&v[4] = *(const float4*)(src + idx + 4);
        *(uint4*)(dst + idx) = pack8(v);
    }
}

// ================= per-user segment sum + bias + tanh -> xb bf16 =================
__global__ __launch_bounds__(256) void agg_kernel(const unsigned char* __restrict__ wtb8,
                                                  const int* __restrict__ offs,
                                                  const int* __restrict__ ends,
                                                  const int2* __restrict__ s_pack,
                                                  const float* __restrict__ b_enc,
                                                  unsigned short* __restrict__ xb) {
    __shared__ float red[3 * 512];
    int u = blockIdx.x;
    int tid = threadIdx.x;
    int g = tid >> 6, lane = tid & 63;
    float acc[8] = {};
    int j0 = offs[u], j1 = ends[u];
    int j = j0 + g;
    int2 nxt = (j < j1) ? s_pack[j] : make_int2(0, 0);
    while (j < j1) {
        int2 cur = nxt;
        int jn = j + 4;
        if (jn < j1) nxt = s_pack[jn];
        float r = __int_as_float(cur.y);
        uint2 v = ((const uint2*)(wtb8 + (size_t)cur.x * H0))[lane];
        float wf[8];
        fp8x4_to_f32(v.x, wf);
        fp8x4_to_f32(v.y, wf + 4);
#pragma unroll
        for (int e = 0; e < 8; ++e) acc[e] += wf[e] * r;
        j = jn;
    }
    if (g) {
        float4* rp = (float4*)red + (size_t)(g - 1) * 128 + lane * 2;
        rp[0] = make_float4(acc[0], acc[1], acc[2], acc[3]);
        rp[1] = make_float4(acc[4], acc[5], acc[6], acc[7]);
    }
    __syncthreads();
    if (g == 0) {
#pragma unroll
        for (int h = 0; h < 3; ++h) {
            const float* rp = red + h * 512 + lane * 8;
#pragma unroll
            for (int e = 0; e < 8; ++e) acc[e] += rp[e];
        }
        float4 b0 = ((const float4*)b_enc)[lane * 2];
        float4 b1 = ((const float4*)b_enc)[lane * 2 + 1];
        float o[8];
        o[0] = tanhf(acc[0] * FP8_INV + b0.x); o[1] = tanhf(acc[1] * FP8_INV + b0.y);
        o[2] = tanhf(acc[2] * FP8_INV + b0.z); o[3] = tanhf(acc[3] * FP8_INV + b0.w);
        o[4] = tanhf(acc[4] * FP8_INV + b1.x); o[5] = tanhf(acc[5] * FP8_INV + b1.y);
        o[6] = tanhf(acc[6] * FP8_INV + b1.z); o[7] = tanhf(acc[7] * FP8_INV + b1.w);
        ((uint4*)(xb + (size_t)u * H0))[lane] = pack8(o);
    }
}

// ================= bf16 MFMA GEMM, 128 x BN tile, tanh epilogue =================
template<int BN>
__global__ __launch_bounds__(256) void gemm_mfma(const unsigned short* __restrict__ A,
                                                 const unsigned short* __restrict__ B,
                                                 const float* __restrict__ bias,
                                                 unsigned short* __restrict__ C,
                                                 int Nn, int K) {
    constexpr int WN = BN / 32;
    constexpr int NCH = 8 + BN / 16;
    constexpr int PER = NCH / 4;
    __shared__ unsigned short Ash[128 * 32];
    __shared__ unsigned short Bsh[BN * 32];
    int tid = threadIdx.x;
    int wid = tid >> 6, lane = tid & 63;
    int wave_m = wid & 1, wave_n = wid >> 1;
    int quad = lane >> 4, l16 = lane & 15;
    int m0 = blockIdx.x * 128, n0 = blockIdx.y * BN;
    floatx4 acc[4][WN] = {};
    int srow = lane >> 2;
    int scol = (lane & 3) * 8;
    for (int k0 = 0; k0 < K; k0 += 32) {
#pragma unroll
        for (int i = 0; i < PER; ++i) {
            int c = wid * PER + i;
            if (c < 8) {
                const unsigned short* ga = A + (size_t)(m0 + c * 16 + srow) * K + k0 + scol;
                __builtin_amdgcn_global_load_lds(
                    (const __attribute__((address_space(1))) void*)ga,
                    (__attribute__((address_space(3))) void*)((__attribute__((address_space(3))) char*)Ash + c * 1024),
                    16, 0, 0);
            } else {
                const unsigned short* gb = B + (size_t)(n0 + (c - 8) * 16 + srow) * K + k0 + scol;
                __builtin_amdgcn_global_load_lds(
                    (const __attribute__((address_space(1))) void*)gb,
                    (__attribute__((address_space(3))) void*)((__attribute__((address_space(3))) char*)Bsh + (c - 8) * 1024),
                    16, 0, 0);
            }
        }
        __syncthreads();
        short8 af[4], bfr[WN];
#pragma unroll
        for (int i = 0; i < 4; ++i) {
            int ml = wave_m * 64 + i * 16 + l16;
            af[i] = ((const short8*)Ash)[ml * 4 + quad];
        }
#pragma unroll
        for (int j = 0; j < WN; ++j) {
            int nl = wave_n * (BN / 2) + j * 16 + l16;
            bfr[j] = ((const short8*)Bsh)[nl * 4 + quad];
        }
#pragma unroll
        for (int i = 0; i < 4; ++i)
#pragma unroll
            for (int j = 0; j < WN; ++j)
                acc[i][j] = __builtin_amdgcn_mfma_f32_16x16x32_bf16(af[i], bfr[j], acc[i][j], 0, 0, 0);
        __syncthreads();
    }
#pragma unroll
    for (int j = 0; j < WN; ++j) {
        int col = n0 + wave_n * (BN / 2) + j * 16 + l16;
        float bv = bias[col];
#pragma unroll
        for (int i = 0; i < 4; ++i) {
            int rowb = m0 + wave_m * 64 + i * 16 + quad * 4;
#pragma unroll
            for (int r = 0; r < 4; ++r)
                C[(size_t)(rowb + r) * Nn + col] = f2bf(tanhf(acc[i][j][r] + bv));
        }
    }
}

// ================= predict: one block per user, decoded row in regs, gather fp8 W rows =================
__global__ __launch_bounds__(256) void predict_kernel(const unsigned short* __restrict__ dec_b,
                                                      const unsigned char* __restrict__ wdb8,
                                                      const float* __restrict__ b_dec,
                                                      const int* __restrict__ offs,
                                                      const int* __restrict__ ends,
                                                      const int4* __restrict__ st,
                                                      float* __restrict__ pred,
                                                      float* __restrict__ loss,
                                                      float invNT) {
    __shared__ float wsum[4];
    int u = blockIdx.x;
    int wid = threadIdx.x >> 6, lane = threadIdx.x & 63;
    int j0 = offs[u], j1 = ends[u];
    float sq = 0.f;
    if (j0 < j1) {
        // this user's decoded row: 8 bf16 per lane (coalesced, L1/L2-hot across the 4 waves)
        uint4 gv = ((const uint4*)(dec_b + (size_t)u * H0))[lane];
        float g[8];
        g[0] = bflo(gv.x); g[1] = bfhi(gv.x);
        g[2] = bflo(gv.y); g[3] = bfhi(gv.y);
        g[4] = bflo(gv.z); g[5] = bfhi(gv.z);
        g[6] = bflo(gv.w); g[7] = bfhi(gv.w);
        int j = j0 + wid;
        int4 nxt = (j < j1) ? st[j] : make_int4(0, 0, 0, 0);
        while (j < j1) {
            int4 tv = nxt;
            int jn = j + 4;
            if (jn < j1) nxt = st[jn];
            uint2 wv = ((const uint2*)(wdb8 + (size_t)tv.x * H0))[lane];
            float wf[8];
            fp8x4_to_f32(wv.x, wf);
            fp8x4_to_f32(wv.y, wf + 4);
            float s = g[0] * wf[0] + g[1] * wf[1] + g[2] * wf[2] + g[3] * wf[3]
                    + g[4] * wf[4] + g[5] * wf[5] + g[6] * wf[6] + g[7] * wf[7];
#pragma unroll
            for (int off = 32; off; off >>= 1) s += __shfl_xor(s, off, 64);
            if (lane == 0) {
                float p = s * FP8_INV + b_dec[tv.x];
                pred[tv.z] = p;
                float d = p - __int_as_float(tv.y);
                sq += d * d;
            }
            j = jn;
        }
    }
    if (lane == 0) wsum[wid] = sq;
    __syncthreads();
    if (threadIdx.x == 0) {
        float t = wsum[0] + wsum[1] + wsum[2] + wsum[3];
        if (t != 0.f) atomicAdd(loss, t * invNT);
    }
}

extern "C" void kernel_launch(void* const* d_in, const int* in_sizes, int n_in,
                              void* d_out, int out_size, void* d_ws, size_t ws_size,
                              hipStream_t stream) {
    const int* user = (const int*)d_in[0];
    const int* item = (const int*)d_in[1];
    const float* rating = (const float*)d_in[2];
    const int* t_user = (const int*)d_in[3];
    const int* t_item = (const int*)d_in[4];
    const float* t_rating = (const float*)d_in[5];
    const float* W_enc = (const float*)d_in[6];
    const float* b_enc = (const float*)d_in[7];
    const float* W1 = (const float*)d_in[8];
    const float* b1 = (const float*)d_in[9];
    const float* W2 = (const float*)d_in[10];
    const float* b2 = (const float*)d_in[11];
    const float* W_dec = (const float*)d_in[12];
    const float* b_dec = (const float*)d_in[13];
    const int N = in_sizes[0];
    const int NT = in_sizes[3];

    char* ws = (char*)d_ws;
    size_t off = 0;
    auto alloc = [&](size_t bytes) {
        void* p = ws + off;
        off = (off + bytes + 255) & ~(size_t)255;
        return p;
    };
    unsigned char* wtb8 = (unsigned char*)alloc((size_t)NUM_ITEMS * H0);        // 25.6 MB
    unsigned char* wdb8 = (unsigned char*)alloc((size_t)NUM_ITEMS * H0);        // 25.6 MB
    unsigned short* xb = (unsigned short*)alloc((size_t)NUM_USERS * H0 * 2);    // 16 MB
    unsigned short* enc_b = (unsigned short*)alloc((size_t)NUM_USERS * LAT * 2);// 8 MB
    unsigned short* dec_b = (unsigned short*)alloc((size_t)NUM_USERS * H0 * 2); // 16 MB
    unsigned short* w1b = (unsigned short*)alloc((size_t)LAT * H0 * 2);
    unsigned short* w2b = (unsigned short*)alloc((size_t)H0 * LAT * 2);
    int* cntU = (int*)alloc((size_t)NUM_USERS * 2 * 4);
    int* cntTU = cntU + NUM_USERS;
    int* offsU = (int*)alloc((size_t)NUM_USERS * 4);
    int* curU = (int*)alloc((size_t)NUM_USERS * 4);
    int* offsTU = (int*)alloc((size_t)NUM_USERS * 4);
    int* curTU = (int*)alloc((size_t)NUM_USERS * 4);
    int2* s_pack = (int2*)alloc((size_t)N * 8);
    int4* st_pack = (int4*)alloc((size_t)NT * 16);

    float* pred = (float*)d_out;
    float* loss = pred + NT;

    const int maxNNT = N > NT ? N : NT;
    const int SB = (maxNNT + 255) / 256;                 // 1024 scatter blocks
    const int TBX = (NUM_ITEMS + 63) / 64;               // 782
    const int TB = TBX * (H0 / 64);                      // 6256 transpose blocks
    const int DB = (NUM_ITEMS * H0) / 4096;              // 6250 W_dec cast blocks
    const int WB = 128;                                  // W1+W2 cast blocks

    hipMemsetAsync(cntU, 0, (size_t)NUM_USERS * 2 * 4, stream);
    hipMemsetAsync(loss, 0, 4, stream);
    count_kernel<<<(maxNNT + 1023) / 1024, 256, 0, stream>>>(user, cntU, t_user, cntTU, N, NT);
    scan_kernel<<<2, 1024, 0, stream>>>(cntU, offsU, curU, cntTU, offsTU, curTU);
    mega_kernel<<<SB + TB + DB + WB, 256, 0, stream>>>(
        user, item, rating, curU, s_pack,
        t_user, t_item, t_rating, curTU, st_pack,
        W_enc, wtb8, W_dec, wdb8, W1, w1b, W2, w2b,
        N, NT, SB, TB, DB);
    agg_kernel<<<NUM_USERS, 256, 0, stream>>>(wtb8, offsU, curU, s_pack, b_enc, xb);
    gemm_mfma<64><<<dim3(NUM_USERS / 128, LAT / 64), 256, 0, stream>>>(xb, w1b, b1, enc_b, LAT, H0);
    gemm_mfma<64><<<dim3(NUM_USERS / 128, H0 / 64), 256, 0, stream>>>(enc_b, w2b, b2, dec_b, H0, LAT);
    predict_kernel<<<NUM_USERS, 256, 0, stream>>>(dec_b, wdb8, b_dec, offsTU, curTU, st_pack, pred, loss, 1.0f / NT);
}

// Round 3
// 422.256 us; speedup vs baseline: 1.3747x; 1.3747x over previous
//
#include <hip/hip_runtime.h>
#include <hip/hip_bf16.h>
#include <math.h>

#define NUM_ITEMS 50000
#define NUM_USERS 16384
#define H0 512
#define LAT 256
#define FP8_SCALE 64.0f   // weights ~±0.011 are subnormal in e4m3; x64 -> ~0.7 (3% rel err)
#define FP8_INV (1.0f / 64.0f)

typedef __attribute__((ext_vector_type(8))) short short8;
typedef __attribute__((ext_vector_type(4))) float floatx4;
typedef __attribute__((ext_vector_type(2))) float vf2;

__device__ __forceinline__ unsigned short f2bf(float f) {
    union { float f; unsigned i; } u; u.f = f;
    unsigned r = u.i + 0x7fff + ((u.i >> 16) & 1);   // RNE
    return (unsigned short)(r >> 16);
}
__device__ __forceinline__ float bfhi(unsigned v) {
    union { unsigned i; float f; } u; u.i = v & 0xffff0000u; return u.f;
}
__device__ __forceinline__ float bflo(unsigned v) {
    union { unsigned i; float f; } u; u.i = v << 16; return u.f;
}
__device__ __forceinline__ uint4 pack8(const float* v) {
    uint4 p;
    p.x = (unsigned)f2bf(v[0]) | ((unsigned)f2bf(v[1]) << 16);
    p.y = (unsigned)f2bf(v[2]) | ((unsigned)f2bf(v[3]) << 16);
    p.z = (unsigned)f2bf(v[4]) | ((unsigned)f2bf(v[5]) << 16);
    p.w = (unsigned)f2bf(v[6]) | ((unsigned)f2bf(v[7]) << 16);
    return p;
}
// pack 4 floats -> 4 fp8 e4m3 (OCP on gfx950)
__device__ __forceinline__ unsigned pkfp8_4(float a, float b, float c, float d) {
    int v = __builtin_amdgcn_cvt_pk_fp8_f32(a, b, 0, false);
    v = __builtin_amdgcn_cvt_pk_fp8_f32(c, d, v, true);
    return (unsigned)v;
}
__device__ __forceinline__ void fp8x4_to_f32(unsigned v, float* o) {
    vf2 lo = __builtin_amdgcn_cvt_pk_f32_fp8((int)v, false);
    vf2 hi = __builtin_amdgcn_cvt_pk_f32_fp8((int)v, true);
    o[0] = lo.x; o[1] = lo.y; o[2] = hi.x; o[3] = hi.y;
}

// ================= count: users (interactions) + users (targets) =================
__global__ __launch_bounds__(256) void count_kernel(const int* __restrict__ user, int* __restrict__ cntU,
                                                    const int* __restrict__ t_user, int* __restrict__ cntTU,
                                                    int n, int nt) {
    int i = (blockIdx.x * blockDim.x + threadIdx.x) * 4;
    if (i + 3 < n) {
        int4 u = *(const int4*)(user + i);
        atomicAdd(&cntU[u.x], 1); atomicAdd(&cntU[u.y], 1);
        atomicAdd(&cntU[u.z], 1); atomicAdd(&cntU[u.w], 1);
    } else {
        for (int k = i; k < n; ++k) atomicAdd(&cntU[user[k]], 1);
    }
    if (i + 3 < nt) {
        int4 t = *(const int4*)(t_user + i);
        atomicAdd(&cntTU[t.x], 1); atomicAdd(&cntTU[t.y], 1);
        atomicAdd(&cntTU[t.z], 1); atomicAdd(&cntTU[t.w], 1);
    } else {
        for (int k = i; k < nt; ++k) atomicAdd(&cntTU[t_user[k]], 1);
    }
}

// ================= dual exclusive scan =================
__device__ void scan_block(const int* __restrict__ cnt, int* __restrict__ offs,
                           int* __restrict__ cursor, int per) {
    __shared__ int ssum[1024];
    int t = threadIdx.x;
    int base = t * per;
    int s = 0;
    for (int j = 0; j < per; j += 4) {
        int4 v = *(const int4*)(cnt + base + j);
        s += v.x + v.y + v.z + v.w;
    }
    ssum[t] = s;
    __syncthreads();
    for (int off = 1; off < 1024; off <<= 1) {
        int v = (t >= off) ? ssum[t - off] : 0;
        __syncthreads();
        ssum[t] += v;
        __syncthreads();
    }
    int run = (t == 0) ? 0 : ssum[t - 1];
    for (int j = 0; j < per; j += 4) {
        int4 v = *(const int4*)(cnt + base + j);
        int4 o;
        o.x = run; run += v.x;
        o.y = run; run += v.y;
        o.z = run; run += v.z;
        o.w = run; run += v.w;
        *(int4*)(offs + base + j) = o;
        *(int4*)(cursor + base + j) = o;
    }
}

__global__ void scan_kernel(const int* __restrict__ cntU, int* __restrict__ offsU, int* __restrict__ curU,
                            const int* __restrict__ cntTU, int* __restrict__ offsTU, int* __restrict__ curTU) {
    if (blockIdx.x == 0) scan_block(cntU, offsU, curU, NUM_USERS / 1024);
    else scan_block(cntTU, offsTU, curTU, NUM_USERS / 1024);
}

// ================= mega kernel: scatter | transpose W_enc -> fp8 | W_dec -> fp8 | W1/W2 -> bf16 =================
// block ranges: [0,SB) scatter ; [SB,SB+TB) transpose ; [SB+TB,+DB) W_dec ; [+WB) W1/W2.
// LDS is 16KB -> 8 blocks/CU (32 waves, full cap) for every block type.
__global__ __launch_bounds__(256) void mega_kernel(
        const int* __restrict__ user, const int* __restrict__ item,
        const float* __restrict__ rating, int* __restrict__ curU, int2* __restrict__ s_pack,
        const int* __restrict__ t_user, const int* __restrict__ t_item,
        const float* __restrict__ t_rating, int* __restrict__ curTU, int4* __restrict__ st_pack,
        const float* __restrict__ W_enc, unsigned char* __restrict__ wtb8,
        const float* __restrict__ W_dec, unsigned char* __restrict__ wdb8,
        const float* __restrict__ W1, unsigned short* __restrict__ w1b,
        const float* __restrict__ W2, unsigned short* __restrict__ w2b,
        int n, int nt, int SB, int TB, int DB) {
    // [h][item] natural layout: float4 LDS stores on the load side (~2-way max),
    // transpose happens on the read side with stride-64 scalar reads (bank = item%32, conflict-free).
    __shared__ float tileh[64 * 64];    // 16 KB
    int bid = blockIdx.x;
    int tid = threadIdx.x;
    if (bid < SB) {
        // ---- scatter: interactions by user (int2), targets by user (int4) ----
        int i = bid * 256 + tid;
        if (i < n) {
            int u = user[i];
            int pos = atomicAdd(&curU[u], 1);
            s_pack[pos] = make_int2(item[i], __float_as_int(rating[i]));
        }
        if (i < nt) {
            int tu = t_user[i];
            int pos = atomicAdd(&curTU[tu], 1);
            st_pack[pos] = make_int4(t_item[i], __float_as_int(t_rating[i]), i, 0);
        }
    } else if (bid < SB + TB) {
        // ---- transpose W_enc [H0][NUM_ITEMS] f32 -> wtb8 [NUM_ITEMS][H0] fp8 (x64), 64it x 64h tiles ----
        const int TBX = (NUM_ITEMS + 63) / 64;   // 782
        int b = bid - SB;
        int x0 = (b % TBX) * 64;        // item base
        int y0 = (b / TBX) * 64;        // h base
        int g = tid >> 4;               // 0..15 h-sub
        int m = tid & 15;               // item quad
        int it4 = x0 + m * 4;
#pragma unroll
        for (int p = 0; p < 4; ++p) {
            int hloc = p * 16 + g;
            if (it4 < NUM_ITEMS) {
                float4 v = *(const float4*)(W_enc + (size_t)(y0 + hloc) * NUM_ITEMS + it4);
                *(float4*)(tileh + hloc * 64 + m * 4) = v;
            }
        }
        __syncthreads();
        int i = tid >> 2;               // item 0..63
        int l = tid & 3;                // 16-element h chunk
        int it = x0 + i;
        if (it < NUM_ITEMS) {
            const float* src = tileh + (l * 16) * 64 + i;   // stride-64 column reads
            uint4 o;
            o.x = pkfp8_4(src[0] * FP8_SCALE, src[64] * FP8_SCALE, src[128] * FP8_SCALE, src[192] * FP8_SCALE);
            o.y = pkfp8_4(src[256] * FP8_SCALE, src[320] * FP8_SCALE, src[384] * FP8_SCALE, src[448] * FP8_SCALE);
            o.z = pkfp8_4(src[512] * FP8_SCALE, src[576] * FP8_SCALE, src[640] * FP8_SCALE, src[704] * FP8_SCALE);
            o.w = pkfp8_4(src[768] * FP8_SCALE, src[832] * FP8_SCALE, src[896] * FP8_SCALE, src[960] * FP8_SCALE);
            *(uint4*)(wtb8 + (size_t)it * H0 + y0 + l * 16) = o;
        }
    } else if (bid < SB + TB + DB) {
        // ---- W_dec f32 -> fp8 (x64), 16 elems/thread, pure streaming ----
        size_t idx = (size_t)(bid - SB - TB) * 4096 + tid * 16;
        float4 v0 = *(const float4*)(W_dec + idx);
        float4 v1 = *(const float4*)(W_dec + idx + 4);
        float4 v2 = *(const float4*)(W_dec + idx + 8);
        float4 v3 = *(const float4*)(W_dec + idx + 12);
        uint4 o;
        o.x = pkfp8_4(v0.x * FP8_SCALE, v0.y * FP8_SCALE, v0.z * FP8_SCALE, v0.w * FP8_SCALE);
        o.y = pkfp8_4(v1.x * FP8_SCALE, v1.y * FP8_SCALE, v1.z * FP8_SCALE, v1.w * FP8_SCALE);
        o.z = pkfp8_4(v2.x * FP8_SCALE, v2.y * FP8_SCALE, v2.z * FP8_SCALE, v2.w * FP8_SCALE);
        o.w = pkfp8_4(v3.x * FP8_SCALE, v3.y * FP8_SCALE, v3.z * FP8_SCALE, v3.w * FP8_SCALE);
        *(uint4*)(wdb8 + idx) = o;
    } else {
        // ---- W1 / W2 cast to bf16, 64 blocks each ----
        int b2i = bid - SB - TB - DB;
        const float* src = (b2i < 64) ? W1 : W2;
        unsigned short* dst = (b2i < 64) ? w1b : w2b;
        int idx = (b2i & 63) * 2048 + tid * 8;
        float v[8];
        *(float4*)&v[0] = *(const float4*)(src + idx);
        *(float4*)&v[4] = *(const float4*)(src + idx + 4);
        *(uint4*)(dst + idx) = pack8(v);
    }
}

// ================= per-user segment sum + bias + tanh -> xb bf16 =================
__global__ __launch_bounds__(256) void agg_kernel(const unsigned char* __restrict__ wtb8,
                                                  const int* __restrict__ offs,
                                                  const int* __restrict__ ends,
                                                  const int2* __restrict__ s_pack,
                                                  const float* __restrict__ b_enc,
                                                  unsigned short* __restrict__ xb) {
    __shared__ float red[3 * 512];
    int u = blockIdx.x;
    int tid = threadIdx.x;
    int g = tid >> 6, lane = tid & 63;
    float acc[8] = {};
    int j0 = offs[u], j1 = ends[u];
    int j = j0 + g;
    int2 nxt = (j < j1) ? s_pack[j] : make_int2(0, 0);
    while (j < j1) {
        int2 cur = nxt;
        int jn = j + 4;
        if (jn < j1) nxt = s_pack[jn];
        float r = __int_as_float(cur.y);
        uint2 v = ((const uint2*)(wtb8 + (size_t)cur.x * H0))[lane];
        float wf[8];
        fp8x4_to_f32(v.x, wf);
        fp8x4_to_f32(v.y, wf + 4);
#pragma unroll
        for (int e = 0; e < 8; ++e) acc[e] += wf[e] * r;
        j = jn;
    }
    if (g) {
        float4* rp = (float4*)red + (size_t)(g - 1) * 128 + lane * 2;
        rp[0] = make_float4(acc[0], acc[1], acc[2], acc[3]);
        rp[1] = make_float4(acc[4], acc[5], acc[6], acc[7]);
    }
    __syncthreads();
    if (g == 0) {
#pragma unroll
        for (int h = 0; h < 3; ++h) {
            const float* rp = red + h * 512 + lane * 8;
#pragma unroll
            for (int e = 0; e < 8; ++e) acc[e] += rp[e];
        }
        float4 b0 = ((const float4*)b_enc)[lane * 2];
        float4 b1 = ((const float4*)b_enc)[lane * 2 + 1];
        float o[8];
        o[0] = tanhf(acc[0] * FP8_INV + b0.x); o[1] = tanhf(acc[1] * FP8_INV + b0.y);
        o[2] = tanhf(acc[2] * FP8_INV + b0.z); o[3] = tanhf(acc[3] * FP8_INV + b0.w);
        o[4] = tanhf(acc[4] * FP8_INV + b1.x); o[5] = tanhf(acc[5] * FP8_INV + b1.y);
        o[6] = tanhf(acc[6] * FP8_INV + b1.z); o[7] = tanhf(acc[7] * FP8_INV + b1.w);
        ((uint4*)(xb + (size_t)u * H0))[lane] = pack8(o);
    }
}

// ================= bf16 MFMA GEMM, 128 x BN tile, tanh epilogue =================
template<int BN>
__global__ __launch_bounds__(256) void gemm_mfma(const unsigned short* __restrict__ A,
                                                 const unsigned short* __restrict__ B,
                                                 const float* __restrict__ bias,
                                                 unsigned short* __restrict__ C,
                                                 int Nn, int K) {
    constexpr int WN = BN / 32;
    constexpr int NCH = 8 + BN / 16;
    constexpr int PER = NCH / 4;
    __shared__ unsigned short Ash[128 * 32];
    __shared__ unsigned short Bsh[BN * 32];
    int tid = threadIdx.x;
    int wid = tid >> 6, lane = tid & 63;
    int wave_m = wid & 1, wave_n = wid >> 1;
    int quad = lane >> 4, l16 = lane & 15;
    int m0 = blockIdx.x * 128, n0 = blockIdx.y * BN;
    floatx4 acc[4][WN] = {};
    int srow = lane >> 2;
    int scol = (lane & 3) * 8;
    for (int k0 = 0; k0 < K; k0 += 32) {
#pragma unroll
        for (int i = 0; i < PER; ++i) {
            int c = wid * PER + i;
            if (c < 8) {
                const unsigned short* ga = A + (size_t)(m0 + c * 16 + srow) * K + k0 + scol;
                __builtin_amdgcn_global_load_lds(
                    (const __attribute__((address_space(1))) void*)ga,
                    (__attribute__((address_space(3))) void*)((__attribute__((address_space(3))) char*)Ash + c * 1024),
                    16, 0, 0);
            } else {
                const unsigned short* gb = B + (size_t)(n0 + (c - 8) * 16 + srow) * K + k0 + scol;
                __builtin_amdgcn_global_load_lds(
                    (const __attribute__((address_space(1))) void*)gb,
                    (__attribute__((address_space(3))) void*)((__attribute__((address_space(3))) char*)Bsh + (c - 8) * 1024),
                    16, 0, 0);
            }
        }
        __syncthreads();
        short8 af[4], bfr[WN];
#pragma unroll
        for (int i = 0; i < 4; ++i) {
            int ml = wave_m * 64 + i * 16 + l16;
            af[i] = ((const short8*)Ash)[ml * 4 + quad];
        }
#pragma unroll
        for (int j = 0; j < WN; ++j) {
            int nl = wave_n * (BN / 2) + j * 16 + l16;
            bfr[j] = ((const short8*)Bsh)[nl * 4 + quad];
        }
#pragma unroll
        for (int i = 0; i < 4; ++i)
#pragma unroll
            for (int j = 0; j < WN; ++j)
                acc[i][j] = __builtin_amdgcn_mfma_f32_16x16x32_bf16(af[i], bfr[j], acc[i][j], 0, 0, 0);
        __syncthreads();
    }
#pragma unroll
    for (int j = 0; j < WN; ++j) {
        int col = n0 + wave_n * (BN / 2) + j * 16 + l16;
        float bv = bias[col];
#pragma unroll
        for (int i = 0; i < 4; ++i) {
            int rowb = m0 + wave_m * 64 + i * 16 + quad * 4;
#pragma unroll
            for (int r = 0; r < 4; ++r)
                C[(size_t)(rowb + r) * Nn + col] = f2bf(tanhf(acc[i][j][r] + bv));
        }
    }
}

// ================= predict: one block per user, decoded row in regs, gather fp8 W rows =================
// NO same-address atomics: per-block partial -> partials[], reduced by loss_reduce.
__global__ __launch_bounds__(256) void predict_kernel(const unsigned short* __restrict__ dec_b,
                                                      const unsigned char* __restrict__ wdb8,
                                                      const float* __restrict__ b_dec,
                                                      const int* __restrict__ offs,
                                                      const int* __restrict__ ends,
                                                      const int4* __restrict__ st,
                                                      float* __restrict__ pred,
                                                      float* __restrict__ partials) {
    __shared__ float wsum[4];
    int u = blockIdx.x;
    int wid = threadIdx.x >> 6, lane = threadIdx.x & 63;
    int j0 = offs[u], j1 = ends[u];
    float sq = 0.f;
    if (j0 < j1) {
        // this user's decoded row: 8 bf16 per lane (coalesced, L1/L2-hot across the 4 waves)
        uint4 gv = ((const uint4*)(dec_b + (size_t)u * H0))[lane];
        float g[8];
        g[0] = bflo(gv.x); g[1] = bfhi(gv.x);
        g[2] = bflo(gv.y); g[3] = bfhi(gv.y);
        g[4] = bflo(gv.z); g[5] = bfhi(gv.z);
        g[6] = bflo(gv.w); g[7] = bfhi(gv.w);
        int j = j0 + wid;
        // depth-2 software pipeline on the target record AND the gathered row
        int4 tv = (j < j1) ? st[j] : make_int4(0, 0, 0, 0);
        uint2 wv = make_uint2(0, 0);
        if (j < j1) wv = ((const uint2*)(wdb8 + (size_t)tv.x * H0))[lane];
        while (j < j1) {
            int jn = j + 4;
            int4 tvn = make_int4(0, 0, 0, 0);
            uint2 wvn = make_uint2(0, 0);
            if (jn < j1) {
                tvn = st[jn];
                wvn = ((const uint2*)(wdb8 + (size_t)tvn.x * H0))[lane];
            }
            float wf[8];
            fp8x4_to_f32(wv.x, wf);
            fp8x4_to_f32(wv.y, wf + 4);
            float s = g[0] * wf[0] + g[1] * wf[1] + g[2] * wf[2] + g[3] * wf[3]
                    + g[4] * wf[4] + g[5] * wf[5] + g[6] * wf[6] + g[7] * wf[7];
#pragma unroll
            for (int off = 32; off; off >>= 1) s += __shfl_xor(s, off, 64);
            if (lane == 0) {
                float p = s * FP8_INV + b_dec[tv.x];
                pred[tv.z] = p;
                float d = p - __int_as_float(tv.y);
                sq += d * d;
            }
            j = jn; tv = tvn; wv = wvn;
        }
    }
    if (lane == 0) wsum[wid] = sq;
    __syncthreads();
    if (threadIdx.x == 0)
        partials[u] = wsum[0] + wsum[1] + wsum[2] + wsum[3];
}

__global__ void loss_reduce(const float* __restrict__ partials, float* __restrict__ out_loss,
                            int nPart, float invNT) {
    __shared__ float s[256];
    int t = threadIdx.x;
    float a = 0.f;
    const float4* p4 = (const float4*)partials;
    int n4 = nPart >> 2;
    for (int i = t; i < n4; i += 256) {
        float4 v = p4[i];
        a += v.x + v.y + v.z + v.w;
    }
    for (int i = (n4 << 2) + t; i < nPart; i += 256) a += partials[i];
    s[t] = a;
    __syncthreads();
    for (int off = 128; off; off >>= 1) {
        if (t < off) s[t] += s[t + off];
        __syncthreads();
    }
    if (t == 0) out_loss[0] = s[0] * invNT;
}

extern "C" void kernel_launch(void* const* d_in, const int* in_sizes, int n_in,
                              void* d_out, int out_size, void* d_ws, size_t ws_size,
                              hipStream_t stream) {
    const int* user = (const int*)d_in[0];
    const int* item = (const int*)d_in[1];
    const float* rating = (const float*)d_in[2];
    const int* t_user = (const int*)d_in[3];
    const int* t_item = (const int*)d_in[4];
    const float* t_rating = (const float*)d_in[5];
    const float* W_enc = (const float*)d_in[6];
    const float* b_enc = (const float*)d_in[7];
    const float* W1 = (const float*)d_in[8];
    const float* b1 = (const float*)d_in[9];
    const float* W2 = (const float*)d_in[10];
    const float* b2 = (const float*)d_in[11];
    const float* W_dec = (const float*)d_in[12];
    const float* b_dec = (const float*)d_in[13];
    const int N = in_sizes[0];
    const int NT = in_sizes[3];

    char* ws = (char*)d_ws;
    size_t off = 0;
    auto alloc = [&](size_t bytes) {
        void* p = ws + off;
        off = (off + bytes + 255) & ~(size_t)255;
        return p;
    };
    unsigned char* wtb8 = (unsigned char*)alloc((size_t)NUM_ITEMS * H0);        // 25.6 MB
    unsigned char* wdb8 = (unsigned char*)alloc((size_t)NUM_ITEMS * H0);        // 25.6 MB
    unsigned short* xb = (unsigned short*)alloc((size_t)NUM_USERS * H0 * 2);    // 16 MB
    unsigned short* enc_b = (unsigned short*)alloc((size_t)NUM_USERS * LAT * 2);// 8 MB
    unsigned short* dec_b = (unsigned short*)alloc((size_t)NUM_USERS * H0 * 2); // 16 MB
    unsigned short* w1b = (unsigned short*)alloc((size_t)LAT * H0 * 2);
    unsigned short* w2b = (unsigned short*)alloc((size_t)H0 * LAT * 2);
    int* cntU = (int*)alloc((size_t)NUM_USERS * 2 * 4);
    int* cntTU = cntU + NUM_USERS;
    int* offsU = (int*)alloc((size_t)NUM_USERS * 4);
    int* curU = (int*)alloc((size_t)NUM_USERS * 4);
    int* offsTU = (int*)alloc((size_t)NUM_USERS * 4);
    int* curTU = (int*)alloc((size_t)NUM_USERS * 4);
    int2* s_pack = (int2*)alloc((size_t)N * 8);
    int4* st_pack = (int4*)alloc((size_t)NT * 16);
    float* partials = (float*)alloc((size_t)NUM_USERS * 4);

    float* pred = (float*)d_out;
    float* loss = pred + NT;

    const int maxNNT = N > NT ? N : NT;
    const int SB = (maxNNT + 255) / 256;                 // 1024 scatter blocks
    const int TBX = (NUM_ITEMS + 63) / 64;               // 782
    const int TB = TBX * (H0 / 64);                      // 6256 transpose blocks
    const int DB = (NUM_ITEMS * H0) / 4096;              // 6250 W_dec cast blocks
    const int WB = 128;                                  // W1+W2 cast blocks

    hipMemsetAsync(cntU, 0, (size_t)NUM_USERS * 2 * 4, stream);
    count_kernel<<<(maxNNT + 1023) / 1024, 256, 0, stream>>>(user, cntU, t_user, cntTU, N, NT);
    scan_kernel<<<2, 1024, 0, stream>>>(cntU, offsU, curU, cntTU, offsTU, curTU);
    mega_kernel<<<SB + TB + DB + WB, 256, 0, stream>>>(
        user, item, rating, curU, s_pack,
        t_user, t_item, t_rating, curTU, st_pack,
        W_enc, wtb8, W_dec, wdb8, W1, w1b, W2, w2b,
        N, NT, SB, TB, DB);
    agg_kernel<<<NUM_USERS, 256, 0, stream>>>(wtb8, offsU, curU, s_pack, b_enc, xb);
    gemm_mfma<64><<<dim3(NUM_USERS / 128, LAT / 64), 256, 0, stream>>>(xb, w1b, b1, enc_b, LAT, H0);
    gemm_mfma<64><<<dim3(NUM_USERS / 128, H0 / 64), 256, 0, stream>>>(enc_b, w2b, b2, dec_b, H0, LAT);
    predict_kernel<<<NUM_USERS, 256, 0, stream>>>(dec_b, wdb8, b_dec, offsTU, curTU, st_pack, pred, partials);
    loss_reduce<<<1, 256, 0, stream>>>(partials, loss, NUM_USERS, 1.0f / NT);
}